// Round 9
// baseline (236602.979 us; speedup 1.0000x reference)
//
#include <hip/hip_runtime.h>
#include <hip/hip_cooperative_groups.h>
#include <math.h>

// Problem constants
#define Bz 512
#define Sz 128
#define Dz 128
#define Hz 1024
#define Lz 128
#define NSUB 4

#define GRID 256
#define BLOCK 512
#define NGRP 16   // independent groups (32 batch rows each)
#define GBLK 16   // blocks per group

typedef _Float16 half8 __attribute__((ext_vector_type(8)));
typedef float floatx4 __attribute__((ext_vector_type(4)));
typedef unsigned long long u64;

#define MFMA16(a, b, c) __builtin_amdgcn_mfma_f32_16x16x32_f16(a, b, c, 0, 0, 0)

// ROUND-9: W is NOT staged through LDS anymore. All weights are pre-converted
// ONCE per call (grid pass + grid.sync) into frag-major f16 hi/lo arrays in
// ws; each wave loads its W fragments directly from L2/IF$, perfectly
// coalesced (lane ln reads 16B at base+ln*16). Only A goes through LDS
// (loaded once per block, shared across waves). Per-chunk LDS b128 ops/wave:
// 22 -> 10; split8 VALU /3. Derivation: for mfma_16x16x32_f16, lane(qd,l16)
// of wave(wr,wc) needs W[col0+wc*16+l16][c*128+(kq*4+qd)*8+0..7] - contiguous.
//
// A-LDS: frag-major hi/lo, 3-bit XOR swizzle (verified conflict-free),
// double-buffered 16KB chunks. 96KB alloc keeps the 1-block/CU guard
// (round-1: 2-block/CU packing halved effective occupancy).
#define ALO_D 4096
#define CHUNK_A 8192
#define LDS_HALFS 49152

enum { EPI_NONE = 0, EPI_Y = 1, EPI_H = 2 };

// dopri5 tableau row i+1 (input coeffs of stage i+1). Row 5 == 5th-order b
// weights (FSAL): h_next = y_6; stage-7 f-eval is dead and skipped.
__constant__ float DPA_C[6][6] = {
  {0.2f, 0.f, 0.f, 0.f, 0.f, 0.f},
  {0.075f, 0.225f, 0.f, 0.f, 0.f, 0.f},
  {44.f/45.f, -56.f/15.f, 32.f/9.f, 0.f, 0.f, 0.f},
  {19372.f/6561.f, -25360.f/2187.f, 64448.f/6561.f, -212.f/729.f, 0.f, 0.f},
  {9017.f/3168.f, -355.f/33.f, 46732.f/5247.f, 49.f/176.f, -5103.f/18656.f, 0.f},
  {35.f/384.f, 0.f, 500.f/1113.f, 125.f/192.f, -2187.f/6784.f, 11.f/84.f},
};

struct KArgs {
  const float *x, *t, *w_ih, *w_hh, *b_ih, *b_hh;
  const float *w0, *b0, *w1, *b1, *w2, *b2, *mu_w, *mu_b, *lv_w, *lv_b;
  float* out;
  float *h, *y, *t1, *t2, *gi, *gh;
  unsigned* bar;   // NGRP * 64 u32: slots[0..15]
  _Float16 *wf0, *wf1, *wf2, *whh, *wih, *muf, *lvf;   // converted weights
};

// ---- IF$-level (cross-XCD coherent) accesses: relaxed agent atomics set
// sc0+sc1 (bypass L1+L2) with NO cache-wiping fences. Weights stay cached.
__device__ __forceinline__ float2 ldc2(const float* p) {
  u64 v = __hip_atomic_load((u64*)p, __ATOMIC_RELAXED, __HIP_MEMORY_SCOPE_AGENT);
  union { u64 u; float2 f; } c; c.u = v; return c.f;
}
__device__ __forceinline__ float ldc1(const float* p) {
  unsigned v = __hip_atomic_load((unsigned*)p, __ATOMIC_RELAXED, __HIP_MEMORY_SCOPE_AGENT);
  union { unsigned u; float f; } c; c.u = v; return c.f;
}
__device__ __forceinline__ void stc1(float* p, float f) {
  union { float f; unsigned u; } c; c.f = f;
  __hip_atomic_store((unsigned*)p, c.u, __ATOMIC_RELAXED, __HIP_MEMORY_SCOPE_AGENT);
}

// Group barrier, all-to-all: each block writes its slot; wave 0 polls all 16
// slots (one coalesced 64B IF$ load/iter). Equality-poll on incrementing
// epochs is poison-safe. vmcnt drain orders the data stores before the flag.
__device__ __forceinline__ void gbar(unsigned* gb, int jj, unsigned e) {
  asm volatile("s_waitcnt vmcnt(0) lgkmcnt(0)" ::: "memory");
  __syncthreads();
  if (threadIdx.x == 0)
    __hip_atomic_store(&gb[jj], e, __ATOMIC_RELAXED, __HIP_MEMORY_SCOPE_AGENT);
  if (threadIdx.x < 64) {
    const int sl = threadIdx.x & 15;
    while (__hip_atomic_load(&gb[sl], __ATOMIC_RELAXED, __HIP_MEMORY_SCOPE_AGENT) != e)
      __builtin_amdgcn_s_sleep(1);
  }
  __syncthreads();
}

__device__ __forceinline__ void split8(float4 a, float4 b, half8& h, half8& l) {
  float v[8] = {a.x, a.y, a.z, a.w, b.x, b.y, b.z, b.w};
#pragma unroll
  for (int i = 0; i < 8; ++i) {
    _Float16 hh = (_Float16)v[i];
    h[i] = hh;
    l[i] = (_Float16)((v[i] - (float)hh) * 2048.0f);
  }
}

// One-time weight conversion: W[n][k] fp32 -> frag-major f16 hi/lo planes.
// dst layout (halfs): block (tile*NC*16 + c*16 + kq*4 + wc) of 512, within it
// lane(qd*16+l16)*8 + j. Reader: contiguous 16B per lane. lo plane at +N*K.
template<int LK>
__device__ void convW(const float* __restrict__ W, int N,
                      _Float16* __restrict__ dst) {
  constexpr int K = 1 << LK;
  constexpr int NC = K >> 7;
  const size_t total = (size_t)N << LK;
  for (size_t idx = (size_t)blockIdx.x * BLOCK + threadIdx.x; idx < total;
       idx += (size_t)GRID * BLOCK) {
    const int n = (int)(idx >> LK);
    const int k = (int)(idx & (K - 1));
    const float v = W[idx];
    const _Float16 h = (_Float16)v;
    const _Float16 l = (_Float16)((v - (float)h) * 2048.0f);
    const int tile = n >> 6, wcq = (n >> 4) & 3, l16 = n & 15;
    const int c = k >> 7, sg = (k >> 3) & 15, kq = sg >> 2, qd = sg & 3, j = k & 7;
    const size_t off = ((size_t)(tile * NC * 16 + c * 16 + kq * 4 + wcq) << 9)
                     + (size_t)(((qd << 4) + l16) << 3) + j;
    dst[off] = h;
    dst[off + total] = l;
  }
}

// One 32x64 tile of C[512,N] = A[512,K] @ W[N,K]^T + bias.
// A fp32 (IF$ if ACo) staged via LDS w/ hi/lo split; W fragments loaded
// directly from the converted array (L2-cached, coalesced). K compile-time.
template<int K, bool ACo>
__device__ __forceinline__ void mfma_tile(
    const float* __restrict__ A, int lda,
    const _Float16* __restrict__ Wf, size_t loOff,
    const float* __restrict__ bias,
    float* __restrict__ Cf, float* __restrict__ Yd, int ldc,
    int act, int epi, int stage, float hs,
    const float* __restrict__ hbuf,
    floatx4& K0, floatx4& K1, floatx4& K2, floatx4& K3, floatx4& K4,
    floatx4& Hc,
    int row0, int tileIdx, _Float16* __restrict__ lds)
{
  constexpr int NC = K >> 7;
  const int tid = threadIdx.x;
  const int ln  = tid & 63;
  const int l16 = ln & 15;
  const int qd  = ln >> 4;
  const int wv  = tid >> 6;
  const int wr  = wv >> 2;     // 0..1 row-group
  const int wc  = wv & 3;      // 0..3 col-group

  // A staging: thread owns one 8-fp32 row-seg; 3-bit XOR bank swizzle
  const int an   = tid >> 4;         // 0..31
  const int an15 = an & 15, ang = an >> 4;
  const int seg  = tid & 15;
  const int c_ = seg >> 2, q_ = seg & 3;
  const int ua = q_ * 16 + (an15 ^ ((q_ << 1) | (c_ & 1)));
  const int aoff = ((c_ * 2 + ang) * 64 + ua) << 3;
  const float* gA = A + (size_t)(row0 + an) * lda + (seg << 3);

  // per-lane W fragment base for this tile/wave (halfs)
  const _Float16* wfb = Wf + ((size_t)tileIdx * NC * 16 + wc) * 512 + (ln << 3);

  floatx4 Phh = {0,0,0,0}, Phl = {0,0,0,0}, Plh = {0,0,0,0}, Pll = {0,0,0,0};

  float4 ra0, ra1;
  auto loadA = [&](int kk) {
    if (ACo) {
      float2 a0 = ldc2(gA + kk),     a1 = ldc2(gA + kk + 2);
      float2 a2 = ldc2(gA + kk + 4), a3 = ldc2(gA + kk + 6);
      ra0 = make_float4(a0.x, a0.y, a1.x, a1.y);
      ra1 = make_float4(a2.x, a2.y, a3.x, a3.y);
    } else {
      ra0 = *(const float4*)(gA + kk);
      ra1 = *(const float4*)(gA + kk + 4);
    }
  };
  auto storeA = [&](int bufo) {
    half8 h, l;
    split8(ra0, ra1, h, l);
    *(half8*)&lds[bufo + aoff] = h;
    *(half8*)&lds[bufo + aoff + ALO_D] = l;
  };

  half8 wh[2][4], wl[2][4];
  auto loadWf = [&](int c, int par) {   // par compile-time under full unroll
#pragma unroll
    for (int kq = 0; kq < 4; ++kq) {
      const _Float16* p = wfb + ((size_t)(c * 16 + kq * 4) << 9);
      wh[par][kq] = *(const half8*)p;
      wl[par][kq] = *(const half8*)(p + loOff);
    }
  };

  loadA(0);
  loadWf(0, 0);                // in flight across the entry barrier
  __syncthreads();             // prior tile's readers done with A buffers
  storeA(0);
  if (NC > 1) loadA(128);

#pragma unroll
  for (int c = 0; c < NC; ++c) {
    __syncthreads();           // A(c) visible; W(c)/A(c+1) loads drained
    if (c + 1 < NC) {
      loadWf(c + 1, (c + 1) & 1);          // hides under chunk-c compute
      storeA(((c + 1) & 1) ? CHUNK_A : 0); // other buffer: no read hazard
      if (c + 2 < NC) loadA((c + 2) << 7);
    }
    const _Float16* __restrict__ lr = lds + ((c & 1) ? CHUNK_A : 0);
#pragma unroll
    for (int kq = 0; kq < 4; ++kq) {
      const int lnw = ln ^ ((qd << 1) | (kq & 1));   // same swizzle as writer
      const int ab = ((kq * 2 + wr) * 64 + lnw) << 3;
      half8 ah = *(const half8*)&lr[ab];
      half8 al = *(const half8*)&lr[ab + ALO_D];
      Phh = MFMA16(ah, wh[c & 1][kq], Phh);
      Phl = MFMA16(ah, wl[c & 1][kq], Phl);
      Plh = MFMA16(al, wh[c & 1][kq], Plh);
      Pll = MFMA16(al, wl[c & 1][kq], Pll);
    }
  }

  // Epilogue. C/D layout: col = lane&15, row = (lane>>4)*4 + i (m89-verified)
  const int col   = (tileIdx << 6) + (wc << 4) + l16;
  const int rbase = row0 + (wr << 4) + (qd << 2);
  const float bb = bias[col];
#pragma unroll
  for (int i = 0; i < 4; ++i) {
    float v = Phh[i] + (Phl[i] + Plh[i]) * (1.0f/2048.0f)
            + Pll[i] * (1.0f/4194304.0f) + bb;
    if (act) v = tanhf(v);
    const size_t off = (size_t)(rbase + i) * ldc + col;
    if (epi == EPI_NONE) {
      stc1(&Cf[off], v);
    } else {
      if (stage == 0) Hc[i] = ldc1(&hbuf[off]);   // fresh h once per substep
      float yv = Hc[i];
      const float* DP = DPA_C[stage];
      if (stage > 0) yv = fmaf(hs * DP[0], K0[i], yv);
      if (stage > 1) { float c1 = DP[1]; if (c1 != 0.f) yv = fmaf(hs * c1, K1[i], yv); }
      if (stage > 2) yv = fmaf(hs * DP[2], K2[i], yv);
      if (stage > 3) yv = fmaf(hs * DP[3], K3[i], yv);
      if (stage > 4) yv = fmaf(hs * DP[4], K4[i], yv);
      yv = fmaf(hs * DP[stage], v, yv);
      if      (stage == 0) K0[i] = v;
      else if (stage == 1) K1[i] = v;
      else if (stage == 2) K2[i] = v;
      else if (stage == 3) K3[i] = v;
      else if (stage == 4) K4[i] = v;
      stc1(&Yd[off], yv);      // y_{stage+1}, or h in place (FSAL, stage 5)
    }
  }
}

template<int K, bool ACo>
__device__ __forceinline__ void run_phase(
    const float* A, int lda,
    const _Float16* Wf, size_t loOff, const float* bias, int N,
    float* Cf, float* Yd, int ldc, int act, int epi, int stage, float hs,
    const float* hbuf,
    floatx4& K0, floatx4& K1, floatx4& K2, floatx4& K3, floatx4& K4,
    floatx4& Hc, int g, int jj, _Float16* lds)
{
  const int tilesN = N >> 6;
  const int row0 = g << 5;     // group owns rows [g*32, g*32+32)
  if (tilesN >= GBLK) {
    const int tn0 = ((jj & 7) << 1) | (jj >> 3);
    for (int i = 0; i < (tilesN >> 4); ++i)
      mfma_tile<K, ACo>(A, lda, Wf, loOff, bias, Cf, Yd, ldc, act, epi, stage,
                        hs, hbuf, K0, K1, K2, K3, K4, Hc,
                        row0, tn0 + (i << 4), lds);
  } else {
    if (jj < tilesN)
      mfma_tile<K, ACo>(A, lda, Wf, loOff, bias, Cf, Yd, ldc, act, epi, stage,
                        hs, hbuf, K0, K1, K2, K3, K4, Hc, row0, jj, lds);
  }
}

__global__ __launch_bounds__(BLOCK, 2) void ode_gru_kernel(KArgs a) {
  __shared__ __align__(16) _Float16 lds[LDS_HALFS];  // 96KB: 1-block/CU guard
  const int g  = blockIdx.x >> 4;
  const int jj = blockIdx.x & 15;
  unsigned* gb = a.bar + (g << 6);
  unsigned ep = 0;

  // zero this group's h rows via IF$ stores (ws poisoned every call)
  for (int i = jj * BLOCK + threadIdx.x; i < 32 * Hz; i += GBLK * BLOCK)
    stc1(a.h + (size_t)g * 32 * Hz + i, 0.f);

  // one-time weight conversion (whole grid cooperates); grid.sync gives the
  // device-scope release/acquire (L2 writeback + invalidate) so plain cached
  // reads of the converted arrays are safe on every XCD.
  convW<10>(a.w0,   Hz,     a.wf0);
  convW<10>(a.w1,   Hz,     a.wf1);
  convW<10>(a.w2,   Hz,     a.wf2);
  convW<10>(a.w_hh, 3 * Hz, a.whh);
  convW<7>(a.w_ih,  3 * Hz, a.wih);
  convW<10>(a.mu_w, Lz,     a.muf);
  convW<10>(a.lv_w, Lz,     a.lvf);
  cooperative_groups::this_grid().sync();

  floatx4 K0 = {0,0,0,0}, K1 = {0,0,0,0}, K2 = {0,0,0,0};
  floatx4 K3 = {0,0,0,0}, K4 = {0,0,0,0}, Hc = {0,0,0,0};

  const size_t LHH = (size_t)Hz * Hz;

  for (int s = 0; s < Sz; ++s) {
    if (s > 0) {
      const float dt = a.t[s] - a.t[s - 1];
      const float hs = dt * (1.0f / NSUB);
      for (int sub = 0; sub < NSUB; ++sub) {
        for (int st = 0; st < 6; ++st) {
          const float* yin = (st == 0) ? a.h : a.y;
          // L1 (tanh)
          run_phase<Hz, true>(yin, Hz, a.wf0, LHH, a.b0, Hz, a.t1, nullptr, Hz,
                              1, EPI_NONE, 0, 0.f, nullptr,
                              K0, K1, K2, K3, K4, Hc, g, jj, lds);
          gbar(gb, jj, ++ep);
          // L2 (tanh)
          run_phase<Hz, true>(a.t1, Hz, a.wf1, LHH, a.b1, Hz, a.t2, nullptr, Hz,
                              1, EPI_NONE, 0, 0.f, nullptr,
                              K0, K1, K2, K3, K4, Hc, g, jj, lds);
          gbar(gb, jj, ++ep);
          // L3 (linear) + fused dopri5 combine; k's stay in registers
          if (st < 5) {
            run_phase<Hz, true>(a.t2, Hz, a.wf2, LHH, a.b2, Hz, nullptr, a.y,
                                Hz, 0, EPI_Y, st, hs, a.h,
                                K0, K1, K2, K3, K4, Hc, g, jj, lds);
          } else {   // FSAL: h_next = y_6, written to h in place
            run_phase<Hz, true>(a.t2, Hz, a.wf2, LHH, a.b2, Hz, nullptr, a.h,
                                Hz, 0, EPI_H, 5, hs, a.h,
                                K0, K1, K2, K3, K4, Hc, g, jj, lds);
          }
          gbar(gb, jj, ++ep);
        }
      }
    }

    // GRU gates: gi = x_s@Wih^T+b ; gh = h@Whh^T+b (independent, one barrier)
    run_phase<Dz, false>(a.x + (size_t)s * Dz, Sz * Dz, a.wih,
                         (size_t)3 * Hz * Dz, a.b_ih, 3 * Hz,
                         a.gi, nullptr, 3 * Hz, 0, EPI_NONE, 0, 0.f, nullptr,
                         K0, K1, K2, K3, K4, Hc, g, jj, lds);
    run_phase<Hz, true>(a.h, Hz, a.whh, (size_t)3 * Hz * Hz, a.b_hh, 3 * Hz,
                        a.gh, nullptr, 3 * Hz, 0, EPI_NONE, 0, 0.f, nullptr,
                        K0, K1, K2, K3, K4, Hc, g, jj, lds);
    gbar(gb, jj, ++ep);

    // GRU pointwise, h updated in place (group-local rows)
    for (int i = jj * BLOCK + threadIdx.x; i < 32 * Hz; i += GBLK * BLOCK) {
      const int r = g * 32 + (i >> 10);
      const int c = i & (Hz - 1);
      const size_t gx = (size_t)r * 3 * Hz + c;
      const size_t hx = (size_t)r * Hz + c;
      const float ir  = ldc1(a.gi + gx);
      const float iz  = ldc1(a.gi + gx + Hz);
      const float inn = ldc1(a.gi + gx + 2 * Hz);
      const float hr  = ldc1(a.gh + gx);
      const float hzv = ldc1(a.gh + gx + Hz);
      const float hnn = ldc1(a.gh + gx + 2 * Hz);
      const float hv  = ldc1(a.h + hx);
      const float rr  = 1.f / (1.f + expf(-(ir + hr)));
      const float zz  = 1.f / (1.f + expf(-(iz + hzv)));
      const float nnv = tanhf(inn + rr * hnn);
      stc1(a.h + hx, (1.f - zz) * nnv + zz * hv);
    }
    gbar(gb, jj, ++ep);
  }

  // Final projections (row-local; blocks jj<2 of each group do 1 tile each)
  run_phase<Hz, true>(a.h, Hz, a.muf, (size_t)Lz * Hz, a.mu_b, Lz,
                      a.out, nullptr, Lz, 0, EPI_NONE, 0, 0.f, nullptr,
                      K0, K1, K2, K3, K4, Hc, g, jj, lds);
  run_phase<Hz, true>(a.h, Hz, a.lvf, (size_t)Lz * Hz, a.lv_b, Lz,
                      a.out + (size_t)Bz * Lz, nullptr, Lz,
                      0, EPI_NONE, 0, 0.f, nullptr,
                      K0, K1, K2, K3, K4, Hc, g, jj, lds);
}

extern "C" void kernel_launch(void* const* d_in, const int* in_sizes, int n_in,
                              void* d_out, int out_size, void* d_ws, size_t ws_size,
                              hipStream_t stream) {
  KArgs a;
  a.x    = (const float*)d_in[0];
  a.t    = (const float*)d_in[1];
  a.w_ih = (const float*)d_in[2];
  a.w_hh = (const float*)d_in[3];
  a.b_ih = (const float*)d_in[4];
  a.b_hh = (const float*)d_in[5];
  a.w0   = (const float*)d_in[6];
  a.b0   = (const float*)d_in[7];
  a.w1   = (const float*)d_in[8];
  a.b1   = (const float*)d_in[9];
  a.w2   = (const float*)d_in[10];
  a.b2   = (const float*)d_in[11];
  a.mu_w = (const float*)d_in[12];
  a.mu_b = (const float*)d_in[13];
  a.lv_w = (const float*)d_in[14];
  a.lv_b = (const float*)d_in[15];
  a.out  = (float*)d_out;

  float* ws = (float*)d_ws;
  const size_t BH = (size_t)Bz * Hz;   // 524288 floats
  a.h  = ws + 0 * BH;
  a.y  = ws + 1 * BH;
  a.t1 = ws + 2 * BH;
  a.t2 = ws + 3 * BH;
  a.gi = ws + 4 * BH;            // [512, 3072] = 3*BH
  a.gh = ws + 7 * BH;            // [512, 3072] = 3*BH
  a.bar = (unsigned*)(ws + 10 * BH);   // 1024 u32

  // converted-weight area: ~27.8 MB of f16 hi/lo planes after bar
  _Float16* cvt = (_Float16*)(ws + 10 * BH + 1024);
  const size_t E1  = (size_t)Hz * Hz;       // 1048576
  const size_t Ehh = 3 * E1;                // 3145728
  const size_t Eih = (size_t)3 * Hz * Dz;   // 393216
  const size_t Emu = (size_t)Lz * Hz;       // 131072
  a.wf0 = cvt;  cvt += 2 * E1;
  a.wf1 = cvt;  cvt += 2 * E1;
  a.wf2 = cvt;  cvt += 2 * E1;
  a.whh = cvt;  cvt += 2 * Ehh;
  a.wih = cvt;  cvt += 2 * Eih;
  a.muf = cvt;  cvt += 2 * Emu;
  a.lvf = cvt;  cvt += 2 * Emu;
  (void)ws_size; (void)in_sizes; (void)n_in; (void)out_size;

  KArgs args_val = a;
  void* params[] = { &args_val };
  hipLaunchCooperativeKernel((void*)ode_gru_kernel, dim3(GRID), dim3(BLOCK),
                             params, 0, stream);
}

// Round 10
// 87762.408 us; speedup vs baseline: 2.6959x; 2.6959x over previous
//
#include <hip/hip_runtime.h>
#include <hip/hip_cooperative_groups.h>
#include <math.h>

// Problem constants
#define Bz 512
#define Sz 128
#define Dz 128
#define Hz 1024
#define Lz 128
#define NSUB 4

#define GRID 256
#define BLOCK 512
#define NGRP 16   // independent groups (32 batch rows each)
#define GBLK 16   // blocks per group

typedef _Float16 half8 __attribute__((ext_vector_type(8)));
typedef float floatx4 __attribute__((ext_vector_type(4)));
typedef unsigned long long u64;

#define MFMA16(a, b, c) __builtin_amdgcn_mfma_f32_16x16x32_f16(a, b, c, 0, 0, 0)

// ROUND-10: steady-state split8 ELIMINATED. Weights are converted once per
// call (grid pass + grid.sync) to f16 hi/lo planes (row-major [N][K] — same
// 4MB/layer L2 footprint as fp32, which baseline sustained fine; round-9's
// failure was frag-direct reads bypassing LDS, NOT the conversion).
// Activations t1/t2/y/h are split ONCE at the producing epilogue into hi/lo
// planes; h also keeps f32 (Hc + GRU pointwise). Staging is now pure 16B
// copies global->LDS — zero conversion VALU per chunk (was ~100 ops/thread).
// Numerics bit-identical: split(v) at producer == split(v) at old consumer.
//
// LDS layout/swizzle/dbuf unchanged from the verified r2/r3 structure:
// frag-major hi/lo, 3-bit XOR swizzle (SQ_LDS_BANK_CONFLICT == 0), 48KB
// chunks double-buffered; 96KB alloc keeps the 1-block/CU placement guard.
#define ALO_D 4096
#define BHI_O 8192
#define BLO_D 8192
#define CHUNK_HALFS 24576
#define LDS_HALFS 49152

enum { EPI_F32 = 0, EPI_T = 1, EPI_Y = 2, EPI_H = 3 };

// dopri5 tableau row i+1 (input coeffs of stage i+1). Row 5 == 5th-order b
// weights (FSAL): h_next = y_6; stage-7 f-eval is dead and skipped.
__constant__ float DPA_C[6][6] = {
  {0.2f, 0.f, 0.f, 0.f, 0.f, 0.f},
  {0.075f, 0.225f, 0.f, 0.f, 0.f, 0.f},
  {44.f/45.f, -56.f/15.f, 32.f/9.f, 0.f, 0.f, 0.f},
  {19372.f/6561.f, -25360.f/2187.f, 64448.f/6561.f, -212.f/729.f, 0.f, 0.f},
  {9017.f/3168.f, -355.f/33.f, 46732.f/5247.f, 49.f/176.f, -5103.f/18656.f, 0.f},
  {35.f/384.f, 0.f, 500.f/1113.f, 125.f/192.f, -2187.f/6784.f, 11.f/84.f},
};

struct KArgs {
  const float *x, *t, *w_ih, *w_hh, *b_ih, *b_hh;
  const float *w0, *b0, *w1, *b1, *w2, *b2, *mu_w, *mu_b, *lv_w, *lv_b;
  float* out;
  float *h, *gi, *gh;
  unsigned* bar;   // NGRP * 64 u32: slots[0..15]
  _Float16 *yh, *yl, *t1h, *t1l, *t2h, *t2l, *hhp, *hlp;   // activation planes
  _Float16 *w0h, *w0l, *w1h, *w1l, *w2h, *w2l;             // weight planes
  _Float16 *whhh, *whhl, *wihh, *wihl, *muh, *mulo, *lvh, *lvl;
};

// ---- IF$-level (cross-XCD coherent) accesses: relaxed agent atomics set
// sc0+sc1 (bypass L1+L2) with NO cache-wiping fences. Weights stay in L2.
__device__ __forceinline__ float ldc1(const float* p) {
  unsigned v = __hip_atomic_load((unsigned*)p, __ATOMIC_RELAXED, __HIP_MEMORY_SCOPE_AGENT);
  union { unsigned u; float f; } c; c.u = v; return c.f;
}
__device__ __forceinline__ void stc1(float* p, float f) {
  union { float f; unsigned u; } c; c.f = f;
  __hip_atomic_store((unsigned*)p, c.u, __ATOMIC_RELAXED, __HIP_MEMORY_SCOPE_AGENT);
}
// 16B plane load via 2x u64 IF$ loads (activation planes cross XCDs)
__device__ __forceinline__ half8 ldc8h(const _Float16* p) {
  union { u64 u[2]; half8 h; } c;
  c.u[0] = __hip_atomic_load((const u64*)p, __ATOMIC_RELAXED, __HIP_MEMORY_SCOPE_AGENT);
  c.u[1] = __hip_atomic_load(((const u64*)p) + 1, __ATOMIC_RELAXED, __HIP_MEMORY_SCOPE_AGENT);
  return c.h;
}
// split v once and store to hi/lo planes (IF$ u16 stores)
__device__ __forceinline__ void sth2(_Float16* ph, _Float16* pl, float v) {
  _Float16 h = (_Float16)v;
  _Float16 l = (_Float16)((v - (float)h) * 2048.0f);
  union { _Float16 f; unsigned short u; } ch, cl; ch.f = h; cl.f = l;
  __hip_atomic_store((unsigned short*)ph, ch.u, __ATOMIC_RELAXED, __HIP_MEMORY_SCOPE_AGENT);
  __hip_atomic_store((unsigned short*)pl, cl.u, __ATOMIC_RELAXED, __HIP_MEMORY_SCOPE_AGENT);
}

// Group barrier, all-to-all: each block writes its slot; wave 0 polls all 16
// slots (one coalesced 64B IF$ load/iter). Equality-poll on incrementing
// epochs is poison-safe. vmcnt drain orders the data stores before the flag.
__device__ __forceinline__ void gbar(unsigned* gb, int jj, unsigned e) {
  asm volatile("s_waitcnt vmcnt(0) lgkmcnt(0)" ::: "memory");
  __syncthreads();
  if (threadIdx.x == 0)
    __hip_atomic_store(&gb[jj], e, __ATOMIC_RELAXED, __HIP_MEMORY_SCOPE_AGENT);
  if (threadIdx.x < 64) {
    const int sl = threadIdx.x & 15;
    while (__hip_atomic_load(&gb[sl], __ATOMIC_RELAXED, __HIP_MEMORY_SCOPE_AGENT) != e)
      __builtin_amdgcn_s_sleep(1);
  }
  __syncthreads();
}

__device__ __forceinline__ void split8(float4 a, float4 b, half8& h, half8& l) {
  float v[8] = {a.x, a.y, a.z, a.w, b.x, b.y, b.z, b.w};
#pragma unroll
  for (int i = 0; i < 8; ++i) {
    _Float16 hh = (_Float16)v[i];
    h[i] = hh;
    l[i] = (_Float16)((v[i] - (float)hh) * 2048.0f);
  }
}

// one-time fp32 -> f16 hi/lo plane conversion (plain stores; grid.sync
// provides the device-scope release so plain cached reads are safe)
__device__ void convW(const float* __restrict__ W, size_t total,
                      _Float16* __restrict__ hi, _Float16* __restrict__ lo) {
  for (size_t i = (size_t)blockIdx.x * BLOCK + threadIdx.x; i < total;
       i += (size_t)GRID * BLOCK) {
    const float v = W[i];
    const _Float16 h = (_Float16)v;
    hi[i] = h;
    lo[i] = (_Float16)((v - (float)h) * 2048.0f);
  }
}

// One 32x64 tile of C[512,N] = A[512,K] @ W[N,K]^T + bias.
// AM=0: A from hi/lo planes via IF$ (pure copy). AM=1: A fp32 + split (x only).
// W always from converted planes (plain cached loads, via LDS as in baseline).
template<int K, int AM>
__device__ __forceinline__ void mfma_tile(
    const float* __restrict__ Af,
    const _Float16* __restrict__ Ahi, const _Float16* __restrict__ Alo, int lda,
    const _Float16* __restrict__ Whi, const _Float16* __restrict__ Wlo,
    const float* __restrict__ bias,
    float* __restrict__ Cf, _Float16* __restrict__ Chi, _Float16* __restrict__ Clo,
    int ldc, int act, int epi, int stage, float hs,
    const float* __restrict__ hbuf,
    floatx4& K0, floatx4& K1, floatx4& K2, floatx4& K3, floatx4& K4,
    floatx4& Hc,
    int row0, int col0, _Float16* __restrict__ lds)
{
  constexpr int NC = K >> 7;
  const int tid = threadIdx.x;
  const int ln  = tid & 63;
  const int l16 = ln & 15;
  const int qd  = ln >> 4;
  const int wv  = tid >> 6;
  const int wr  = wv >> 2;     // 0..1 row-group
  const int wc  = wv & 3;      // 0..3 col-group

  // staging: thread owns 8-elem k-segments: 1 A row-seg + 2 W col-segs
  const int an   = tid >> 4;         // 0..31
  const int an15 = an & 15, ang = an >> 4;
  const int seg  = tid & 15;
  const int c_ = seg >> 2, q_ = seg & 3;
  // 3-bit bank swizzle: unit&7 distinct for all 8 (c_&1,q_) combos per octet
  const int ua = q_ * 16 + (an15 ^ ((q_ << 1) | (c_ & 1)));
  const int aoff  = (((c_ * 2 + ang) * 64 + ua) << 3);
  const int boff0 = BHI_O + (((c_ * 4 + ang) * 64 + ua) << 3);
  const int boff1 = BHI_O + (((c_ * 4 + 2 + ang) * 64 + ua) << 3);

  const float*    gA  = Af  + (size_t)(row0 + an) * lda + (seg << 3);
  const _Float16* gAh = Ahi + (size_t)(row0 + an) * lda + (seg << 3);
  const _Float16* gAl = Alo + (size_t)(row0 + an) * lda + (seg << 3);
  const _Float16* gW0h = Whi + (size_t)(col0 + an) * K + (seg << 3);
  const _Float16* gW0l = Wlo + (size_t)(col0 + an) * K + (seg << 3);
  const _Float16* gW1h = Whi + (size_t)(col0 + 32 + an) * K + (seg << 3);
  const _Float16* gW1l = Wlo + (size_t)(col0 + 32 + an) * K + (seg << 3);

  floatx4 Phh = {0,0,0,0}, Phl = {0,0,0,0}, Plh = {0,0,0,0}, Pll = {0,0,0,0};

  half8 rah, ral, rw0h, rw0l, rw1h, rw1l;
  float4 ra0, ra1;
  auto load6 = [&](int kk) {
    if (AM == 0) {
      rah = ldc8h(gAh + kk);
      ral = ldc8h(gAl + kk);
    } else {
      ra0 = *(const float4*)(gA + kk);
      ra1 = *(const float4*)(gA + kk + 4);
    }
    rw0h = *(const half8*)(gW0h + kk); rw0l = *(const half8*)(gW0l + kk);
    rw1h = *(const half8*)(gW1h + kk); rw1l = *(const half8*)(gW1l + kk);
  };
  auto store6 = [&](int bufo) {
    if (AM == 1) { half8 h, l; split8(ra0, ra1, h, l); rah = h; ral = l; }
    *(half8*)&lds[bufo + aoff]  = rah;
    *(half8*)&lds[bufo + aoff + ALO_D]  = ral;
    *(half8*)&lds[bufo + boff0] = rw0h;
    *(half8*)&lds[bufo + boff0 + BLO_D] = rw0l;
    *(half8*)&lds[bufo + boff1] = rw1h;
    *(half8*)&lds[bufo + boff1 + BLO_D] = rw1l;
  };

  load6(0);
  __syncthreads();             // prior tile's readers done with both buffers
  store6(0);
  if (NC > 1) load6(128);

#pragma unroll
  for (int c = 0; c < NC; ++c) {
    __syncthreads();           // buf[c&1] writes drained+visible
    if (c + 1 < NC) {
      store6(((c + 1) & 1) ? CHUNK_HALFS : 0);   // other buffer
      if (c + 2 < NC) load6((c + 2) << 7);
    }
    const _Float16* __restrict__ lr = lds + ((c & 1) ? CHUNK_HALFS : 0);
#pragma unroll
    for (int kq = 0; kq < 4; ++kq) {
      const int lnw = ln ^ ((qd << 1) | (kq & 1));     // same swizzle as writer
      const int ab = ((kq * 2 + wr) * 64 + lnw) << 3;
      const int bb = BHI_O + (((kq * 4 + wc) * 64 + lnw) << 3);
      half8 ah = *(const half8*)&lr[ab];
      half8 al = *(const half8*)&lr[ab + ALO_D];
      half8 bh = *(const half8*)&lr[bb];
      half8 bl = *(const half8*)&lr[bb + BLO_D];
      Phh = MFMA16(ah, bh, Phh);
      Phl = MFMA16(ah, bl, Phl);
      Plh = MFMA16(al, bh, Plh);
      Pll = MFMA16(al, bl, Pll);
    }
  }

  // Epilogue. C/D layout: col = lane&15, row = (lane>>4)*4 + i (m89-verified)
  const int col   = col0 + (wc << 4) + l16;
  const int rbase = row0 + (wr << 4) + (qd << 2);
  const float bb = bias[col];
#pragma unroll
  for (int i = 0; i < 4; ++i) {
    float v = Phh[i] + (Phl[i] + Plh[i]) * (1.0f/2048.0f)
            + Pll[i] * (1.0f/4194304.0f) + bb;
    if (act) v = tanhf(v);
    const size_t off = (size_t)(rbase + i) * ldc + col;
    if (epi == EPI_F32) {
      stc1(&Cf[off], v);
    } else if (epi == EPI_T) {
      sth2(Chi + off, Clo + off, v);         // t1/t2: planes only
    } else {
      if (stage == 0) Hc[i] = ldc1(&hbuf[off]);   // fresh h once per substep
      float yv = Hc[i];
      const float* DP = DPA_C[stage];
      if (stage > 0) yv = fmaf(hs * DP[0], K0[i], yv);
      if (stage > 1) { float c1 = DP[1]; if (c1 != 0.f) yv = fmaf(hs * c1, K1[i], yv); }
      if (stage > 2) yv = fmaf(hs * DP[2], K2[i], yv);
      if (stage > 3) yv = fmaf(hs * DP[3], K3[i], yv);
      if (stage > 4) yv = fmaf(hs * DP[4], K4[i], yv);
      yv = fmaf(hs * DP[stage], v, yv);
      if      (stage == 0) K0[i] = v;
      else if (stage == 1) K1[i] = v;
      else if (stage == 2) K2[i] = v;
      else if (stage == 3) K3[i] = v;
      else if (stage == 4) K4[i] = v;
      if (epi == EPI_H) stc1(&Cf[off], yv);  // f32 h for Hc/GRU
      sth2(Chi + off, Clo + off, yv);        // planes for next A-read
    }
  }
}

template<int K, int AM>
__device__ __forceinline__ void run_phase(
    const float* Af, const _Float16* Ahi, const _Float16* Alo, int lda,
    const _Float16* Whi, const _Float16* Wlo, const float* bias, int N,
    float* Cf, _Float16* Chi, _Float16* Clo, int ldc,
    int act, int epi, int stage, float hs, const float* hbuf,
    floatx4& K0, floatx4& K1, floatx4& K2, floatx4& K3, floatx4& K4,
    floatx4& Hc, int g, int jj, _Float16* lds)
{
  const int tilesN = N >> 6;
  const int row0 = g << 5;     // group owns rows [g*32, g*32+32)
  if (tilesN >= GBLK) {
    const int tn0 = ((jj & 7) << 1) | (jj >> 3);
    for (int i = 0; i < (tilesN >> 4); ++i)
      mfma_tile<K, AM>(Af, Ahi, Alo, lda, Whi, Wlo, bias, Cf, Chi, Clo, ldc,
                       act, epi, stage, hs, hbuf, K0, K1, K2, K3, K4, Hc,
                       row0, (tn0 + (i << 4)) << 6, lds);
  } else {
    if (jj < tilesN)
      mfma_tile<K, AM>(Af, Ahi, Alo, lda, Whi, Wlo, bias, Cf, Chi, Clo, ldc,
                       act, epi, stage, hs, hbuf, K0, K1, K2, K3, K4, Hc,
                       row0, jj << 6, lds);
  }
}

__global__ __launch_bounds__(BLOCK, 2) void ode_gru_kernel(KArgs a) {
  __shared__ __align__(16) _Float16 lds[LDS_HALFS];  // 96KB: dbuf + 1-blk/CU guard
  const int g  = blockIdx.x >> 4;
  const int jj = blockIdx.x & 15;
  unsigned* gb = a.bar + (g << 6);
  unsigned ep = 0;

  // zero this group's h (f32 + planes); visibility via grid.sync below
  for (int i = jj * BLOCK + threadIdx.x; i < 32 * Hz; i += GBLK * BLOCK) {
    const size_t o = (size_t)g * 32 * Hz + i;
    stc1(a.h + o, 0.f);
    sth2(a.hhp + o, a.hlp + o, 0.f);
  }

  // one-time weight conversion (whole grid); grid.sync = device-scope
  // release/acquire so plain cached reads of planes are safe on every XCD.
  const size_t E1 = (size_t)Hz * Hz, Ehh = 3 * E1;
  const size_t Eih = (size_t)3 * Hz * Dz, Emu = (size_t)Lz * Hz;
  convW(a.w0,   E1,  a.w0h,  a.w0l);
  convW(a.w1,   E1,  a.w1h,  a.w1l);
  convW(a.w2,   E1,  a.w2h,  a.w2l);
  convW(a.w_hh, Ehh, a.whhh, a.whhl);
  convW(a.w_ih, Eih, a.wihh, a.wihl);
  convW(a.mu_w, Emu, a.muh,  a.mulo);
  convW(a.lv_w, Emu, a.lvh,  a.lvl);
  cooperative_groups::this_grid().sync();

  floatx4 K0 = {0,0,0,0}, K1 = {0,0,0,0}, K2 = {0,0,0,0};
  floatx4 K3 = {0,0,0,0}, K4 = {0,0,0,0}, Hc = {0,0,0,0};

  for (int s = 0; s < Sz; ++s) {
    if (s > 0) {
      const float dt = a.t[s] - a.t[s - 1];
      const float hs = dt * (1.0f / NSUB);
      for (int sub = 0; sub < NSUB; ++sub) {
        for (int st = 0; st < 6; ++st) {
          const _Float16* ah = (st == 0) ? a.hhp : a.yh;
          const _Float16* al = (st == 0) ? a.hlp : a.yl;
          // L1 (tanh) -> t1 planes
          run_phase<Hz, 0>(nullptr, ah, al, Hz, a.w0h, a.w0l, a.b0, Hz,
                           nullptr, a.t1h, a.t1l, Hz, 1, EPI_T, 0, 0.f, nullptr,
                           K0, K1, K2, K3, K4, Hc, g, jj, lds);
          gbar(gb, jj, ++ep);
          // L2 (tanh) -> t2 planes
          run_phase<Hz, 0>(nullptr, a.t1h, a.t1l, Hz, a.w1h, a.w1l, a.b1, Hz,
                           nullptr, a.t2h, a.t2l, Hz, 1, EPI_T, 0, 0.f, nullptr,
                           K0, K1, K2, K3, K4, Hc, g, jj, lds);
          gbar(gb, jj, ++ep);
          // L3 (linear) + fused dopri5 combine; k's stay in registers
          if (st < 5) {
            run_phase<Hz, 0>(nullptr, a.t2h, a.t2l, Hz, a.w2h, a.w2l, a.b2, Hz,
                             nullptr, a.yh, a.yl, Hz, 0, EPI_Y, st, hs, a.h,
                             K0, K1, K2, K3, K4, Hc, g, jj, lds);
          } else {   // FSAL: h_next = y_6 -> h f32 + planes
            run_phase<Hz, 0>(nullptr, a.t2h, a.t2l, Hz, a.w2h, a.w2l, a.b2, Hz,
                             a.h, a.hhp, a.hlp, Hz, 0, EPI_H, 5, hs, a.h,
                             K0, K1, K2, K3, K4, Hc, g, jj, lds);
          }
          gbar(gb, jj, ++ep);
        }
      }
    }

    // GRU gates: gi = x_s@Wih^T+b ; gh = h@Whh^T+b (independent, one barrier)
    run_phase<Dz, 1>(a.x + (size_t)s * Dz, nullptr, nullptr, Sz * Dz,
                     a.wihh, a.wihl, a.b_ih, 3 * Hz,
                     a.gi, nullptr, nullptr, 3 * Hz, 0, EPI_F32, 0, 0.f, nullptr,
                     K0, K1, K2, K3, K4, Hc, g, jj, lds);
    run_phase<Hz, 0>(nullptr, a.hhp, a.hlp, Hz, a.whhh, a.whhl, a.b_hh, 3 * Hz,
                     a.gh, nullptr, nullptr, 3 * Hz, 0, EPI_F32, 0, 0.f, nullptr,
                     K0, K1, K2, K3, K4, Hc, g, jj, lds);
    gbar(gb, jj, ++ep);

    // GRU pointwise, h updated in place (group-local rows): f32 + planes
    for (int i = jj * BLOCK + threadIdx.x; i < 32 * Hz; i += GBLK * BLOCK) {
      const int r = g * 32 + (i >> 10);
      const int c = i & (Hz - 1);
      const size_t gx = (size_t)r * 3 * Hz + c;
      const size_t hx = (size_t)r * Hz + c;
      const float ir  = ldc1(a.gi + gx);
      const float iz  = ldc1(a.gi + gx + Hz);
      const float inn = ldc1(a.gi + gx + 2 * Hz);
      const float hr  = ldc1(a.gh + gx);
      const float hzv = ldc1(a.gh + gx + Hz);
      const float hnn = ldc1(a.gh + gx + 2 * Hz);
      const float hv  = ldc1(a.h + hx);
      const float rr  = 1.f / (1.f + expf(-(ir + hr)));
      const float zz  = 1.f / (1.f + expf(-(iz + hzv)));
      const float nnv = tanhf(inn + rr * hnn);
      const float hn  = (1.f - zz) * nnv + zz * hv;
      stc1(a.h + hx, hn);
      sth2(a.hhp + hx, a.hlp + hx, hn);
    }
    gbar(gb, jj, ++ep);
  }

  // Final projections (row-local; blocks jj<2 of each group do 1 tile each)
  run_phase<Hz, 0>(nullptr, a.hhp, a.hlp, Hz, a.muh, a.mulo, a.mu_b, Lz,
                   a.out, nullptr, nullptr, Lz, 0, EPI_F32, 0, 0.f, nullptr,
                   K0, K1, K2, K3, K4, Hc, g, jj, lds);
  run_phase<Hz, 0>(nullptr, a.hhp, a.hlp, Hz, a.lvh, a.lvl, a.lv_b, Lz,
                   a.out + (size_t)Bz * Lz, nullptr, nullptr, Lz,
                   0, EPI_F32, 0, 0.f, nullptr,
                   K0, K1, K2, K3, K4, Hc, g, jj, lds);
}

extern "C" void kernel_launch(void* const* d_in, const int* in_sizes, int n_in,
                              void* d_out, int out_size, void* d_ws, size_t ws_size,
                              hipStream_t stream) {
  KArgs a;
  a.x    = (const float*)d_in[0];
  a.t    = (const float*)d_in[1];
  a.w_ih = (const float*)d_in[2];
  a.w_hh = (const float*)d_in[3];
  a.b_ih = (const float*)d_in[4];
  a.b_hh = (const float*)d_in[5];
  a.w0   = (const float*)d_in[6];
  a.b0   = (const float*)d_in[7];
  a.w1   = (const float*)d_in[8];
  a.b1   = (const float*)d_in[9];
  a.w2   = (const float*)d_in[10];
  a.b2   = (const float*)d_in[11];
  a.mu_w = (const float*)d_in[12];
  a.mu_b = (const float*)d_in[13];
  a.lv_w = (const float*)d_in[14];
  a.lv_b = (const float*)d_in[15];
  a.out  = (float*)d_out;

  float* ws = (float*)d_ws;
  const size_t BH = (size_t)Bz * Hz;   // 524288
  a.h  = ws;                     // [512,1024] f32
  a.gi = ws + BH;                // [512,3072] f32
  a.gh = ws + 4 * BH;            // [512,3072] f32
  a.bar = (unsigned*)(ws + 7 * BH);    // 1024 u32 (4KB)

  _Float16* hv = (_Float16*)(ws + 7 * BH + 1024);
  a.yh  = hv; hv += BH;  a.yl  = hv; hv += BH;
  a.t1h = hv; hv += BH;  a.t1l = hv; hv += BH;
  a.t2h = hv; hv += BH;  a.t2l = hv; hv += BH;
  a.hhp = hv; hv += BH;  a.hlp = hv; hv += BH;
  const size_t E1 = (size_t)Hz * Hz, Ehh = 3 * E1;
  const size_t Eih = (size_t)3 * Hz * Dz, Emu = (size_t)Lz * Hz;
  a.w0h = hv; hv += E1;  a.w0l = hv; hv += E1;
  a.w1h = hv; hv += E1;  a.w1l = hv; hv += E1;
  a.w2h = hv; hv += E1;  a.w2l = hv; hv += E1;
  a.whhh = hv; hv += Ehh; a.whhl = hv; hv += Ehh;
  a.wihh = hv; hv += Eih; a.wihl = hv; hv += Eih;
  a.muh = hv; hv += Emu; a.mulo = hv; hv += Emu;
  a.lvh = hv; hv += Emu; a.lvl = hv; hv += Emu;
  (void)ws_size; (void)in_sizes; (void)n_in; (void)out_size;

  KArgs args_val = a;
  void* params[] = { &args_val };
  hipLaunchCooperativeKernel((void*)ode_gru_kernel, dim3(GRID), dim3(BLOCK),
                             params, 0, stream);
}